// Round 13
// baseline (1176.928 us; speedup 1.0000x reference)
//
#include <hip/hip_runtime.h>
#include <math.h>

#define DIM 512
#define NLAYERS 6
#define KSZ 15
#define VOCAB 32000
#define BATCH 2
#define SEQ 1024
#define HIDN 1024
#define RANK 64
#define NTOK (BATCH*SEQ)
#define MIXW 0.1f

typedef unsigned short u16;
typedef _Float16 f16;
typedef _Float16 f16x8 __attribute__((ext_vector_type(8)));
typedef _Float16 f16x4 __attribute__((ext_vector_type(4)));
typedef float  f32x4  __attribute__((ext_vector_type(4)));

__device__ __forceinline__ float sigm(float x){ return 1.f/(1.f+__expf(-x)); }

__device__ __forceinline__ float wred(float v){
  #pragma unroll
  for (int o=32;o>0;o>>=1) v += __shfl_xor(v, o, 64);
  return v;
}

#define MFMA16(a,b,c) __builtin_amdgcn_mfma_f32_16x16x32_f16(a,b,c,0,0,0)

// async global->LDS, 16B per lane, dest = wave-uniform base + lane*16
__device__ __forceinline__ void gld16(const f16* g, f16* l){
  __builtin_amdgcn_global_load_lds(
      (const __attribute__((address_space(1))) void*)g,
      (__attribute__((address_space(3))) void*)l, 16, 0, 0);
}

// counted vmem wait + raw barrier + scheduler fence (T4; rule #18 fence)
template<int N> __device__ __forceinline__ void vwait(){
  asm volatile("s_waitcnt vmcnt(%0)" :: "i"(N) : "memory");
}
__device__ __forceinline__ void pipe_bar(){
  __builtin_amdgcn_s_barrier();
  __builtin_amdgcn_sched_barrier(0);
}
#define SBAR() __builtin_amdgcn_sched_barrier(0)

// ---------------- f32 -> f16 weight conversion ----------------
__global__ __launch_bounds__(256) void k_cvt(const float* __restrict__ s,
    f16* __restrict__ d, long n4){
  long i = (long)blockIdx.x*256 + threadIdx.x;
  if (i >= n4) return;
  float4 v = reinterpret_cast<const float4*>(s)[i];
  f16x4 o; o.x=(f16)v.x; o.y=(f16)v.y; o.z=(f16)v.z; o.w=(f16)v.w;
  reinterpret_cast<f16x4*>(d)[i] = o;
}

// conv weight transpose: cwT[l][m][d] = cw[l][d][KSZ-1-m]
__global__ __launch_bounds__(256) void k_cvtconv(const float* __restrict__ cw,
    float* __restrict__ cwT, int n){
  int i = blockIdx.x*256 + threadIdx.x;
  if (i >= n) return;
  int d = i & (DIM-1); int m = (i >> 9) % KSZ; int l = i / (KSZ*DIM);
  cwT[i] = cw[((size_t)l*DIM + d)*KSZ + (KSZ-1-m)];
}

// ---------------- front-end ----------------
__global__ __launch_bounds__(64) void k_embnorm(const int* __restrict__ idx,
    const float* __restrict__ emb, const float* __restrict__ pos,
    const float* __restrict__ w, float* __restrict__ out){
  int row = blockIdx.x;                 // b*SEQ + t
  int t = row & (SEQ-1);
  int lane = threadIdx.x;
  long ebase = (long)idx[row]*DIM;
  long pbase = (long)t*DIM;
  float v[8]; float ss = 0.f;
  #pragma unroll
  for (int c=0;c<2;c++){
    int d = c*256 + lane*4;
    float4 e = *reinterpret_cast<const float4*>(emb + ebase + d);
    float4 p = *reinterpret_cast<const float4*>(pos + pbase + d);
    float x0 = e.x+p.x, x1 = e.y+p.y, x2 = e.z+p.z, x3 = e.w+p.w;
    v[c*4+0]=x0; v[c*4+1]=x1; v[c*4+2]=x2; v[c*4+3]=x3;
    ss += x0*x0 + x1*x1 + x2*x2 + x3*x3;
  }
  ss = wred(ss);
  float rs = rsqrtf(ss*(1.f/DIM) + 1e-6f);
  long ob = (long)row*DIM;
  #pragma unroll
  for (int c=0;c<2;c++){
    int d = c*256 + lane*4;
    float4 wv = *reinterpret_cast<const float4*>(w + d);
    float4 o;
    o.x = v[c*4+0]*rs*wv.x; o.y = v[c*4+1]*rs*wv.y;
    o.z = v[c*4+2]*rs*wv.z; o.w = v[c*4+3]*rs*wv.w;
    *reinterpret_cast<float4*>(out + ob + d) = o;
  }
}

__global__ void k_mem(const float* __restrict__ p, const float* __restrict__ gw,
                      const float* __restrict__ gb, float* __restrict__ mem){
  int i = blockIdx.x*blockDim.x + threadIdx.x;
  if (i >= BATCH*DIM) return;
  int b = i >> 9, d = i & (DIM-1);
  float acc = gb[d];
  const float* wr = gw + (long)d*DIM;
  const float* pr = p + b*DIM;
  for (int k=0;k<DIM;k+=4){
    float4 wv = *reinterpret_cast<const float4*>(wr+k);
    float4 pv = *reinterpret_cast<const float4*>(pr+k);
    acc += wv.x*pv.x + wv.y*pv.y + wv.z*pv.z + wv.w*pv.w;
  }
  mem[i] = sigm(acc);
}

__global__ void k_shift(const float* __restrict__ xn, const float* __restrict__ mem,
    const float* __restrict__ ts, float* __restrict__ out){
  int i = blockIdx.x*256 + threadIdx.x;   // over NTOK*DIM
  int d = i & (DIM-1); int row = i >> 9; int t = row & (SEQ-1); int b = row >> 10;
  float cur = xn[i];
  float v;
  if (t == 0) v = cur;
  else { float f = ts[d]; v = f*xn[i-DIM] + (1.f-f)*cur; }
  out[i] = v + mem[b*DIM + d];
}

// ---------------- norms / pid (f32 in, f16 out) ----------------
__global__ __launch_bounds__(64) void k_rms(const float* __restrict__ x,
    const float* __restrict__ w, f16* __restrict__ oh){
  int row = blockIdx.x; int lane = threadIdx.x;
  const float* xr = x + (long)row*DIM;
  float v[8]; float ss = 0.f;
  #pragma unroll
  for (int c=0;c<2;c++){
    int d = c*256 + lane*4;
    float4 f = *reinterpret_cast<const float4*>(xr + d);
    v[c*4+0]=f.x; v[c*4+1]=f.y; v[c*4+2]=f.z; v[c*4+3]=f.w;
    ss += f.x*f.x + f.y*f.y + f.z*f.z + f.w*f.w;
  }
  ss = wred(ss);
  float rs = rsqrtf(ss*(1.f/DIM) + 1e-6f);
  long ob = (long)row*DIM;
  #pragma unroll
  for (int c=0;c<2;c++){
    int d = c*256 + lane*4;
    float4 wv = *reinterpret_cast<const float4*>(w + d);
    f16x4 o;
    o.x = (f16)(v[c*4+0]*rs*wv.x); o.y = (f16)(v[c*4+1]*rs*wv.y);
    o.z = (f16)(v[c*4+2]*rs*wv.z); o.w = (f16)(v[c*4+3]*rs*wv.w);
    *reinterpret_cast<f16x4*>(oh + ob + d) = o;
  }
}

// cur_in = rmsnorm(silu(kp*C + ki*(I/i)), gn);  h1 = f16(rmsnorm(cur_in, nw))
__global__ __launch_bounds__(64) void k_pid(const float* __restrict__ C,
    const float* __restrict__ I, float inv_i,
    const float* __restrict__ kp, const float* __restrict__ ki,
    const float* __restrict__ gn, const float* __restrict__ nw,
    float* __restrict__ xin, f16* __restrict__ oh){
  int row = blockIdx.x; int lane = threadIdx.x;
  long base = (long)row*DIM;
  float u[8]; float ss = 0.f;
  #pragma unroll
  for (int c=0;c<2;c++){
    int d = c*256 + lane*4;
    float4 cv = *reinterpret_cast<const float4*>(C + base + d);
    float4 iv = *reinterpret_cast<const float4*>(I + base + d);
    float4 kpv = *reinterpret_cast<const float4*>(kp + d);
    float4 kiv = *reinterpret_cast<const float4*>(ki + d);
    float p0 = kpv.x*cv.x + kiv.x*(iv.x*inv_i);
    float p1 = kpv.y*cv.y + kiv.y*(iv.y*inv_i);
    float p2 = kpv.z*cv.z + kiv.z*(iv.z*inv_i);
    float p3 = kpv.w*cv.w + kiv.w*(iv.w*inv_i);
    float s0 = p0*sigm(p0), s1 = p1*sigm(p1), s2 = p2*sigm(p2), s3 = p3*sigm(p3);
    u[c*4+0]=s0; u[c*4+1]=s1; u[c*4+2]=s2; u[c*4+3]=s3;
    ss += s0*s0 + s1*s1 + s2*s2 + s3*s3;
  }
  ss = wred(ss);
  float rs1 = rsqrtf(ss*(1.f/DIM) + 1e-6f);
  float x2[8]; float ss2 = 0.f;
  #pragma unroll
  for (int c=0;c<2;c++){
    int d = c*256 + lane*4;
    float4 gv = *reinterpret_cast<const float4*>(gn + d);
    float y0 = u[c*4+0]*rs1*gv.x, y1 = u[c*4+1]*rs1*gv.y;
    float y2 = u[c*4+2]*rs1*gv.z, y3 = u[c*4+3]*rs1*gv.w;
    x2[c*4+0]=y0; x2[c*4+1]=y1; x2[c*4+2]=y2; x2[c*4+3]=y3;
    ss2 += y0*y0 + y1*y1 + y2*y2 + y3*y3;
    float4 o; o.x=y0; o.y=y1; o.z=y2; o.w=y3;
    *reinterpret_cast<float4*>(xin + base + d) = o;
  }
  ss2 = wred(ss2);
  float rs2 = rsqrtf(ss2*(1.f/DIM) + 1e-6f);
  #pragma unroll
  for (int c=0;c<2;c++){
    int d = c*256 + lane*4;
    float4 nv = *reinterpret_cast<const float4*>(nw + d);
    f16x4 o;
    o.x = (f16)(x2[c*4+0]*rs2*nv.x); o.y = (f16)(x2[c*4+1]*rs2*nv.y);
    o.z = (f16)(x2[c*4+2]*rs2*nv.z); o.w = (f16)(x2[c*4+3]*rs2*nv.w);
    *reinterpret_cast<f16x4*>(oh + base + d) = o;
  }
}

// ---------------- depthwise causal conv + silu, 8-wide vectorized ----------------
__global__ __launch_bounds__(256) void k_conv(const f16* __restrict__ h1,
    const float* __restrict__ cwT, const float* __restrict__ cb,
    f16* __restrict__ hc, int dil){
  int i = blockIdx.x*256 + threadIdx.x;   // over NTOK*DIM/8
  int d8 = (i & 63) << 3; int row = i >> 6; int t = row & (SEQ-1);
  float acc[8];
  {
    float4 b0 = *reinterpret_cast<const float4*>(&cb[d8]);
    float4 b1 = *reinterpret_cast<const float4*>(&cb[d8+4]);
    acc[0]=b0.x; acc[1]=b0.y; acc[2]=b0.z; acc[3]=b0.w;
    acc[4]=b1.x; acc[5]=b1.y; acc[6]=b1.z; acc[7]=b1.w;
  }
  #pragma unroll
  for (int m=0;m<KSZ;m++){
    if (t - m*dil >= 0){
      f16x8 h = *reinterpret_cast<const f16x8*>(&h1[(size_t)(row - m*dil)*DIM + d8]);
      float4 w0 = *reinterpret_cast<const float4*>(&cwT[m*DIM + d8]);
      float4 w1 = *reinterpret_cast<const float4*>(&cwT[m*DIM + d8 + 4]);
      acc[0]+=w0.x*(float)h[0]; acc[1]+=w0.y*(float)h[1];
      acc[2]+=w0.z*(float)h[2]; acc[3]+=w0.w*(float)h[3];
      acc[4]+=w1.x*(float)h[4]; acc[5]+=w1.y*(float)h[5];
      acc[6]+=w1.z*(float)h[6]; acc[7]+=w1.w*(float)h[7];
    }
  }
  f16x8 o;
  #pragma unroll
  for (int j=0;j<8;j++){ o[j] = (f16)(acc[j]*sigm(acc[j])); }
  *reinterpret_cast<f16x8*>(&hc[(size_t)row*DIM + d8]) = o;
}

// ===== GEMMs: A depth-1 reg prefetch, B gld16 multi-buf, group-counted vmcnt, fewer barriers =====

// ---- dual: G = f16(silu(A.W1^T) * (A.W3^T)); A[2048][512], W[1024][512] ----
// BM=64 (4 waves M-split), BN=32 (both mats), BK=64, NT=8. LDS 32KB -> 5 blocks/CU.
__global__ __launch_bounds__(256) void k_dual(const f16* __restrict__ A,
    const f16* __restrict__ W1, const f16* __restrict__ W3, f16* __restrict__ G){
  __shared__ __align__(16) f16 smem[4*4096];   // 32KB: 4 bufs x (2 mats x 32 x 64)
  int tid = threadIdx.x, lane = tid&63, wid = tid>>6;
  int m0 = blockIdx.x*64, n0 = blockIdx.y*32;
  int r16 = lane&15, kq = lane>>4;
  const f16* arow = A + (size_t)(m0 + wid*16 + r16)*512;

  f16x8 areg[2][2];
#define DALOAD(B,T) { \
    areg[B][0] = *reinterpret_cast<const f16x8*>(arow + (T)*64 + (0*4+kq)*8); \
    areg[B][1] = *reinterpret_cast<const f16x8*>(arow + (T)*64 + (1*4+kq)*8); }

  auto stage = [&](int buf, int t){
    #pragma unroll
    for (int j=0;j<2;j++){
      int cc = j*256 + tid;                 // 512 chunks: [mat][32 rows][8 slots]
      int mat = cc>>8, c2 = cc&255, r = c2>>3, s = c2&7;
      const f16* src = (mat ? W3 : W1) + (size_t)(n0+r)*512 + t*64 + ((s^(r&7))<<3);
      gld16(src, smem + buf*4096 + cc*8);
    }
  };
  f32x4 a1[2] = {}, a3[2] = {};
#define DCOMP(T) { \
    const f16* sbt = smem + ((T)&3)*4096; \
    _Pragma("unroll") \
    for (int kk=0;kk<2;kk++){ \
      int kp0 = kk*4 + kq; \
      _Pragma("unroll") \
      for (int nf=0;nf<2;nf++){ \
        int row = nf*16 + r16; \
        f16x8 b1 = *reinterpret_cast<const f16x8*>(&sbt[row*64 + ((kp0^(row&7))<<3)]); \
        f16x8 b3 = *reinterpret_cast<const f16x8*>(&sbt[2048 + row*64 + ((kp0^(row&7))<<3)]); \
        a1[nf] = MFMA16(areg[(T)&1][kk], b1, a1[nf]); \
        a3[nf] = MFMA16(areg[(T)&1][kk], b3, a3[nf]); \
      } \
    } }
  // prologue, order pinned: [A0][S0][S1][S2]
  DALOAD(0,0); SBAR();
  stage(0,0); SBAR(); stage(1,1); SBAR(); stage(2,2);
#define DITER(T,NW) { vwait<NW>(); pipe_bar(); \
    if ((T)+1 < 8) DALOAD(((T)+1)&1, (T)+1); SBAR(); \
    if ((T)+3 < 8) stage(((T)+3)&3, (T)+3); \
    DCOMP(T); }
  DITER(0,4) DITER(1,2) DITER(2,2) DITER(3,2) DITER(4,2) DITER(5,2) DITER(6,0) DITER(7,0)
#undef DITER
#undef DCOMP
#undef DALOAD
  __syncthreads();
  // epilogue: wave-private staging (stride 36), one-pass coalesced f16x8 writes
  float* stg = (float*)smem + wid*576;
  int dr = (lane>>4)*4, dc = lane&15;
  #pragma unroll
  for (int nf=0;nf<2;nf++)
    #pragma unroll
    for (int q=0;q<4;q++){
      float x1 = a1[nf][q];
      stg[(dr+q)*36 + nf*16 + dc] = x1*sigm(x1)*a3[nf][q];
    }
  int gmb = m0 + wid*16;
  {
    int rr = lane>>2, c = 8*(lane&3);
    float4 lo = *reinterpret_cast<float4*>(&stg[rr*36 + c]);
    float4 hi = *reinterpret_cast<float4*>(&stg[rr*36 + c + 4]);
    f16x8 o;
    o[0]=(f16)lo.x; o[1]=(f16)lo.y; o[2]=(f16)lo.z; o[3]=(f16)lo.w;
    o[4]=(f16)hi.x; o[5]=(f16)hi.y; o[6]=(f16)hi.z; o[7]=(f16)hi.w;
    *reinterpret_cast<f16x8*>(&G[(size_t)(gmb+rr)*HIDN + n0 + c]) = o;
  }
}

// ---- w2: val = A.W2^T + XIN; OF=val; I = (init? XIN : I) + val ----
// A[2048][1024], W2[512][1024]. BM=64 (4 waves M-split), BN=32, BK=128, NT=8.
__global__ __launch_bounds__(256) void k_w2(const f16* __restrict__ A,
    const f16* __restrict__ W, const float* __restrict__ XIN,
    float* __restrict__ OF, float* __restrict__ I, int init){
  __shared__ __align__(16) f16 smem[4*4096];   // 32KB: 4 bufs x (32 x 128)
  int tid = threadIdx.x, lane = tid&63, wid = tid>>6;
  int m0 = blockIdx.x*64, n0 = blockIdx.y*32;
  int r16 = lane&15, kq = lane>>4;
  const f16* arow = A + (size_t)(m0 + wid*16 + r16)*1024;

  f16x8 areg[2][4];
#define WALOAD(B,T) { \
    areg[B][0] = *reinterpret_cast<const f16x8*>(arow + (T)*128 + (0*4+kq)*8); \
    areg[B][1] = *reinterpret_cast<const f16x8*>(arow + (T)*128 + (1*4+kq)*8); \
    areg[B][2] = *reinterpret_cast<const f16x8*>(arow + (T)*128 + (2*4+kq)*8); \
    areg[B][3] = *reinterpret_cast<const f16x8*>(arow + (T)*128 + (3*4+kq)*8); }

  auto stage = [&](int buf, int t){
    #pragma unroll
    for (int j=0;j<2;j++){
      int cc = j*256 + tid;
      int r = cc>>4, s = cc&15;
      int g = (s&8) | ((s^(r&7))&7);
      const f16* src = W + (size_t)(n0+r)*1024 + t*128 + (g<<3);
      gld16(src, smem + buf*4096 + cc*8);
    }
  };
  f32x4 acc[2] = {};
#define WCOMP(T) { \
    const f16* sbt = smem + ((T)&3)*4096; \
    _Pragma("unroll") \
    for (int kk=0;kk<4;kk++){ \
      int kp0 = kk*4 + kq; \
      _Pragma("unroll") \
      for (int nf=0;nf<2;nf++){ \
        int row = nf*16 + r16; \
        int sl = (kp0&8) | ((kp0^(row&7))&7); \
        f16x8 bv = *reinterpret_cast<const f16x8*>(&sbt[row*128 + (sl<<3)]); \
        acc[nf] = MFMA16(areg[(T)&1][kk], bv, acc[nf]); \
      } \
    } }
  WALOAD(0,0); SBAR();
  stage(0,0); SBAR(); stage(1,1); SBAR(); stage(2,2);
#define WITER(T,NW) { vwait<NW>(); pipe_bar(); \
    if ((T)+1 < 8) WALOAD(((T)+1)&1, (T)+1); SBAR(); \
    if ((T)+3 < 8) stage(((T)+3)&3, (T)+3); \
    WCOMP(T); }
  WITER(0,4) WITER(1,2) WITER(2,2) WITER(3,2) WITER(4,2) WITER(5,2) WITER(6,0) WITER(7,0)
#undef WITER
#undef WCOMP
#undef WALOAD
  __syncthreads();
  float* stg = (float*)smem + wid*576;
  int dr = (lane>>4)*4, dc = lane&15;
  #pragma unroll
  for (int nf=0;nf<2;nf++)
    #pragma unroll
    for (int q=0;q<4;q++)
      stg[(dr+q)*36 + nf*16 + dc] = acc[nf][q];
  int gmb = m0 + wid*16;
  #pragma unroll
  for (int pass=0;pass<2;pass++){
    int rr = pass*8 + (lane>>3), c = 4*(lane&7);
    float4 v = *reinterpret_cast<float4*>(&stg[rr*36 + c]);
    size_t o = (size_t)(gmb+rr)*DIM + n0 + c;
    float4 x = *reinterpret_cast<const float4*>(&XIN[o]);
    v.x+=x.x; v.y+=x.y; v.z+=x.z; v.w+=x.w;
    *reinterpret_cast<float4*>(&OF[o]) = v;
    float4 iv;
    if (init) iv = x;
    else      iv = *reinterpret_cast<const float4*>(&I[o]);
    iv.x+=v.x; iv.y+=v.y; iv.z+=v.z; iv.w+=v.w;
    *reinterpret_cast<float4*>(&I[o]) = iv;
  }
}

// ---- logits: OF = A.E^T; A[2048][512], E[32000][512]. BM=256, 8 M-split waves. ----
// BK=128, NT=4: half the barriers; 3 B-bufs (48KB, depth-2), 2 A-bufs (depth-1).
__global__ __launch_bounds__(512) void k_logits(const f16* __restrict__ A,
    const f16* __restrict__ E, float* __restrict__ OF){
  __shared__ __align__(16) f16 sB[3*8192];     // 48KB; epilogue staging overlays
  int tid = threadIdx.x, lane = tid&63, wid = tid>>6;
  int bid = blockIdx.x;
  int m0 = (bid&7)*256, n0 = (bid>>3)*64;      // XCD stripe on m (R11 mapping)
  int r16 = lane&15, kq = lane>>4;
  const f16* arow0 = A + (size_t)(m0 + wid*32 +      r16)*512;
  const f16* arow1 = A + (size_t)(m0 + wid*32 + 16 + r16)*512;

  f16x8 areg[2][2][4];
#define LALOAD(B,T) { \
    _Pragma("unroll") \
    for (int kk=0;kk<4;kk++){ \
      areg[B][0][kk] = *reinterpret_cast<const f16x8*>(arow0 + (T)*128 + (kk*4+kq)*8); \
      areg[B][1][kk] = *reinterpret_cast<const f16x8*>(arow1 + (T)*128 + (kk*4+kq)*8); \
    } }

  auto stage = [&](int buf, int t){           // 64 rows x 128 k f16 = 1024 chunks
    #pragma unroll
    for (int j=0;j<2;j++){
      int cc = j*512 + tid;
      int r = cc>>4, s = cc&15;
      int g = (s&8) | ((s^(r&7))&7);
      gld16(E + (size_t)(n0+r)*512 + t*128 + (g<<3), sB + buf*8192 + cc*8);
    }
  };
  f32x4 acc[2][4] = {};
#define LCOMP(T) { \
    const f16* sbt = sB + ((T)%3)*8192; \
    _Pragma("unroll") \
    for (int kk=0;kk<4;kk++){ \
      int kp0 = kk*4 + kq; \
      _Pragma("unroll") \
      for (int nf=0;nf<4;nf++){ \
        int row = nf*16 + r16; \
        int sl = (kp0&8) | ((kp0^(row&7))&7); \
        f16x8 bv = *reinterpret_cast<const f16x8*>(&sbt[row*128 + (sl<<3)]); \
        acc[0][nf] = MFMA16(areg[(T)&1][0][kk], bv, acc[0][nf]); \
        acc[1][nf] = MFMA16(areg[(T)&1][1][kk], bv, acc[1][nf]); \
      } \
    } }
  LALOAD(0,0); SBAR();
  stage(0,0); SBAR(); stage(1,1);
#define LITER(T,NW) { vwait<NW>(); pipe_bar(); \
    if ((T)+1 < 4) LALOAD(((T)+1)&1, (T)+1); SBAR(); \
    if ((T)+2 < 4) stage(((T)+2)%3, (T)+2); \
    LCOMP(T); }
  LITER(0,2) LITER(1,2) LITER(2,2) LITER(3,0)
#undef LITER
#undef LCOMP
#undef LALOAD
  __syncthreads();
  int dr = (lane>>4)*4, dc = lane&15;
  float* stg = (float*)sB + wid*1088;
  #pragma unroll
  for (int mf=0;mf<2;mf++){
    #pragma unroll
    for (int nf=0;nf<4;nf++)
      #pragma unroll
      for (int q=0;q<4;q++)
        stg[(dr+q)*68 + nf*16 + dc] = acc[mf][nf][q];
    int gmb = m0 + wid*32 + mf*16;
    #pragma unroll
    for (int pass=0;pass<4;pass++){
      int rr = pass*4 + (lane>>4), c = 4*(lane&15);
      float4 v = *reinterpret_cast<float4*>(&stg[rr*68 + c]);
      *reinterpret_cast<float4*>(&OF[(size_t)(gmb+rr)*VOCAB + n0 + c]) = v;
    }
  }
}

// ---------------- mix: parallel scan, one wave per (b,d) column ----------------
__global__ __launch_bounds__(64) void k_mix(float* __restrict__ x){
  int col = blockIdx.x;                 // 0..BATCH*DIM-1
  int b = col >> 9, d = col & (DIM-1);
  int lane = threadIdx.x;
  long o = (long)b*SEQ*DIM + d + (long)lane*16*DIM;
  float v[16]; float s = 0.f;
  #pragma unroll
  for (int j=0;j<16;j++){ v[j] = x[o + (long)j*DIM]; s += v[j]; }
  float t = s;
  #pragma unroll
  for (int off=1; off<64; off<<=1){
    float u = __shfl_up(t, off, 64);
    if (lane >= off) t += u;
  }
  float run = t - s;   // exclusive prefix
  #pragma unroll
  for (int j=0;j<16;j++){
    run += v[j];
    int tt = lane*16 + j;
    x[o + (long)j*DIM] = v[j] + MIXW*run/(float)(tt+1);
  }
}

// ---------------- sgate (low-rank gate) ----------------
__global__ __launch_bounds__(256) void k_sgate(const float* __restrict__ xnew,
    const float* __restrict__ xold, const float* __restrict__ nw,
    const float* __restrict__ dw, const float* __restrict__ db,
    const float* __restrict__ uw, const float* __restrict__ ub,
    float* __restrict__ out){
  __shared__ float raw[DIM];
  __shared__ float xn[DIM];
  __shared__ float part[256];
  __shared__ float hb[RANK];
  int row = blockIdx.x, tid = threadIdx.x;
  long base = (long)row*DIM;
  float ss = 0.f;
  for (int d=tid; d<DIM; d+=256){ float v = xnew[base+d]; raw[d]=v; ss += v*v; }
  ss = wred(ss);
  if ((tid&63)==0) part[tid>>6] = ss;
  __syncthreads();
  float tot = part[0]+part[1]+part[2]+part[3];
  float rs = rsqrtf(tot*(1.f/DIM)+1e-6f);
  for (int d=tid; d<DIM; d+=256) xn[d] = raw[d]*rs*nw[d];
  __syncthreads();
  int rr = tid & 63, q = tid >> 6;
  float p = 0.f;
  const float* dwr = dw + (long)rr*DIM + q*128;
  const float* xq = xn + q*128;
  #pragma unroll 8
  for (int d=0; d<128; d+=4){
    float4 wv = *reinterpret_cast<const float4*>(dwr+d);
    p += xq[d]*wv.x + xq[d+1]*wv.y + xq[d+2]*wv.z + xq[d+3]*wv.w;
  }
  part[tid] = p;
  __syncthreads();
  if (tid < RANK){
    float h = part[tid] + part[64+tid] + part[128+tid] + part[192+tid] + db[tid];
    hb[tid] = h * sigm(h);
  }
  __syncthreads();
  for (int d=tid; d<DIM; d+=256){
    float a = ub[d];
    const float* ur = uw + (long)d*RANK;
    #pragma unroll
    for (int rj=0;rj<RANK;rj+=4){
      float4 uv = *reinterpret_cast<const float4*>(ur+rj);
      a += hb[rj]*uv.x + hb[rj+1]*uv.y + hb[rj+2]*uv.z + hb[rj+3]*uv.w;
    }
    float g = sigm(a);
    out[base+d] = g*raw[d] + (1.f-g)*xold[base+d];
  }
}

// ---------------- host orchestration ----------------
extern "C" void kernel_launch(void* const* d_in, const int* in_sizes, int n_in,
                              void* d_out, int out_size, void* d_ws, size_t ws_size,
                              hipStream_t stream){
  const int*   idx           = (const int*)d_in[0];
  const float* emb           = (const float*)d_in[1];
  const float* pos           = (const float*)d_in[2];
  const float* emb_norm_w    = (const float*)d_in[3];
  const float* token_shift   = (const float*)d_in[4];
  const float* mem_gate_w    = (const float*)d_in[5];
  const float* mem_gate_b    = (const float*)d_in[6];
  const float* memory_p      = (const float*)d_in[7];
  const float* sg_norm       = (const float*)d_in[8];
  const float* sg_down_w     = (const float*)d_in[9];
  const float* sg_down_b     = (const float*)d_in[10];
  const float* sg_up_w       = (const float*)d_in[11];
  const float* sg_up_b       = (const float*)d_in[12];
  const float* final_norm_w  = (const float*)d_in[13];
  struct StackP { const float *nw, *cw, *cb, *w1, *w2, *w3, *kp, *ki, *gn; };
  StackP up { (const float*)d_in[14], (const float*)d_in[15], (const float*)d_in[16],
              (const float*)d_in[17], (const float*)d_in[18], (const float*)d_in[19],
              (const float*)d_in[20], (const float*)d_in[21], (const float*)d_in[23] };
  StackP dn { (const float*)d_in[24], (const float*)d_in[25], (const float*)d_in[26],
              (const float*)d_in[27], (const float*)d_in[28], (const float*)d_in[29],
              (const float*)d_in[30], (const float*)d_in[31], (const float*)d_in[33] };

  char* wp = (char*)d_ws;
  auto alloc = [&](size_t bytes)->void*{
    void* p = (void*)wp; wp += (bytes + 255) & ~(size_t)255; return p;
  };
  float* A0  = (float*)alloc((size_t)NTOK*DIM*4);
  float* A1  = (float*)alloc((size_t)NTOK*DIM*4);
  float* Cb  = (float*)alloc((size_t)NTOK*DIM*4);
  float* Ib  = (float*)alloc((size_t)NTOK*DIM*4);
  float* XIN = (float*)alloc((size_t)NTOK*DIM*4);
  f16*   H1  = (f16*)alloc((size_t)NTOK*DIM*2);
  f16*   HC  = (f16*)alloc((size_t)NTOK*DIM*2);
  f16*   G   = (f16*)alloc((size_t)NTOK*HIDN*2);
  const size_t WSZ = (size_t)NLAYERS*HIDN*DIM;   // per weight family per stack
  f16*   UpW1 = (f16*)alloc(WSZ*2);
  f16*   UpW2 = (f16*)alloc(WSZ*2);
  f16*   UpW3 = (f16*)alloc(WSZ*2);
  f16*   DnW1 = (f16*)alloc(WSZ*2);
  f16*   DnW2 = (f16*)alloc(WSZ*2);
  f16*   DnW3 = (f16*)alloc(WSZ*2);
  f16*   Ef   = (f16*)alloc((size_t)VOCAB*DIM*2);
  float* UpCT = (float*)alloc((size_t)NLAYERS*KSZ*DIM*4);
  float* DnCT = (float*)alloc((size_t)NLAYERS*KSZ*DIM*4);
  float* MEM  = (float*)alloc((size_t)BATCH*DIM*4);

  static const int updil[NLAYERS] = {1,2,4,8,16,32};
  static const int dndil[NLAYERS] = {32,16,8,4,2,1};

  // one-time weight conversions
  {
    long n4 = WSZ/4;
    int g = (int)((n4 + 255)/256);
    k_cvt<<<g,256,0,stream>>>(up.w1, UpW1, n4);
    k_cvt<<<g,256,0,stream>>>(up.w2, UpW2, n4);
    k_cvt<<<g,256,0,stream>>>(up.w3, UpW3, n4);
    k_cvt<<<g,256,0,stream>>>(dn.w1, DnW1, n4);
    k_cvt<<<g,256,0,stream>>>(dn.w2, DnW2, n4);
    k_cvt<<<g,256,0,stream>>>(dn.w3, DnW3, n4);
    long e4 = (long)VOCAB*DIM/4;
    k_cvt<<<(int)((e4+255)/256),256,0,stream>>>(emb, Ef, e4);
    int nc = NLAYERS*KSZ*DIM;
    k_cvtconv<<<(nc+255)/256,256,0,stream>>>(up.cw, UpCT, nc);
    k_cvtconv<<<(nc+255)/256,256,0,stream>>>(dn.cw, DnCT, nc);
  }

  k_embnorm<<<NTOK,64,0,stream>>>(idx, emb, pos, emb_norm_w, Cb);
  k_mem<<<(BATCH*DIM+255)/256,256,0,stream>>>(memory_p, mem_gate_w, mem_gate_b, MEM);
  k_shift<<<NTOK*DIM/256,256,0,stream>>>(Cb, MEM, token_shift, A0);

  auto run_stack = [&](const float* xs, const StackP& S, const float* CT,
                       const f16* W1f, const f16* W2f, const f16* W3f, const int* dil){
    for (int l=0;l<NLAYERS;l++){
      const float* bin;
      if (l==0){
        bin = xs;
        k_rms<<<NTOK,64,0,stream>>>(xs, S.nw + l*DIM, H1);
      } else {
        k_pid<<<NTOK,64,0,stream>>>(Cb, Ib, 1.f/(float)l,
            S.kp+(l-1)*DIM, S.ki+(l-1)*DIM, S.gn+(l-1)*DIM, S.nw+l*DIM, XIN, H1);
        bin = XIN;
      }
      k_conv<<<NTOK*DIM/8/256,256,0,stream>>>(H1, CT + (size_t)l*KSZ*DIM, S.cb + l*DIM, HC, dil[l]);
      k_dual<<<dim3(NTOK/64, HIDN/32),256,0,stream>>>(
          HC, W1f + (size_t)l*HIDN*DIM, W3f + (size_t)l*HIDN*DIM, G);
      k_w2<<<dim3(NTOK/64, DIM/32),256,0,stream>>>(
          G, W2f + (size_t)l*DIM*HIDN, bin, Cb, Ib, (l==0)?1:0);
    }
  };

  // stack 1 (up)
  run_stack(A0, up, UpCT, UpW1, UpW2, UpW3, updil);
  k_mix<<<BATCH*DIM,64,0,stream>>>(Cb);
  k_sgate<<<NTOK,256,0,stream>>>(Cb, A0, sg_norm, sg_down_w, sg_down_b, sg_up_w, sg_up_b, A1);
  // stack 2 (down)
  run_stack(A1, dn, DnCT, DnW1, DnW2, DnW3, dndil);
  k_mix<<<BATCH*DIM,64,0,stream>>>(Cb);
  k_sgate<<<NTOK,256,0,stream>>>(Cb, A0, sg_norm+DIM, sg_down_w+RANK*DIM, sg_down_b+RANK,
                                 sg_up_w+DIM*RANK, sg_up_b+DIM, A1);
  // stack 3 (up again)
  run_stack(A1, up, UpCT, UpW1, UpW2, UpW3, updil);
  k_mix<<<BATCH*DIM,64,0,stream>>>(Cb);
  k_sgate<<<NTOK,256,0,stream>>>(Cb, A1, sg_norm+2*DIM, sg_down_w+2*RANK*DIM, sg_down_b+2*RANK,
                                 sg_up_w+2*DIM*RANK, sg_up_b+2*DIM, Cb);
  // final norm + logits (XCD-striped: bid&7 = m-stripe of 256 rows)
  k_rms<<<NTOK,64,0,stream>>>(Cb, final_norm_w, H1);
  k_logits<<<8*(VOCAB/64),512,0,stream>>>(H1, Ef, (float*)d_out);
}

// Round 14
// 1060.016 us; speedup vs baseline: 1.1103x; 1.1103x over previous
//
#include <hip/hip_runtime.h>
#include <math.h>

#define DIM 512
#define NLAYERS 6
#define KSZ 15
#define VOCAB 32000
#define BATCH 2
#define SEQ 1024
#define HIDN 1024
#define RANK 64
#define NTOK (BATCH*SEQ)
#define MIXW 0.1f

typedef unsigned short u16;
typedef _Float16 f16;
typedef _Float16 f16x8 __attribute__((ext_vector_type(8)));
typedef _Float16 f16x4 __attribute__((ext_vector_type(4)));
typedef float  f32x4  __attribute__((ext_vector_type(4)));

__device__ __forceinline__ float sigm(float x){ return 1.f/(1.f+__expf(-x)); }

__device__ __forceinline__ float wred(float v){
  #pragma unroll
  for (int o=32;o>0;o>>=1) v += __shfl_xor(v, o, 64);
  return v;
}

#define MFMA16(a,b,c) __builtin_amdgcn_mfma_f32_16x16x32_f16(a,b,c,0,0,0)

// async global->LDS, 16B per lane, dest = uniform base + lane*16
__device__ __forceinline__ void gld16(const f16* g, f16* l){
  __builtin_amdgcn_global_load_lds(
      (const __attribute__((address_space(1))) void*)g,
      (__attribute__((address_space(3))) void*)l, 16, 0, 0);
}

// ---------------- f32 -> f16 weight conversion (fused, 6 matrices) ----------------
__global__ __launch_bounds__(256) void k_cvt6(
    const float* __restrict__ s0, const float* __restrict__ s1, const float* __restrict__ s2,
    const float* __restrict__ s3, const float* __restrict__ s4, const float* __restrict__ s5,
    f16* __restrict__ d0, f16* __restrict__ d1, f16* __restrict__ d2,
    f16* __restrict__ d3, f16* __restrict__ d4, f16* __restrict__ d5, long n4){
  long i = (long)blockIdx.x*256 + threadIdx.x;
  if (i >= n4) return;
  const float* s; f16* d;
  switch (blockIdx.y){
    case 0: s=s0; d=d0; break;
    case 1: s=s1; d=d1; break;
    case 2: s=s2; d=d2; break;
    case 3: s=s3; d=d3; break;
    case 4: s=s4; d=d4; break;
    default: s=s5; d=d5; break;
  }
  float4 v = reinterpret_cast<const float4*>(s)[i];
  f16x4 o; o.x=(f16)v.x; o.y=(f16)v.y; o.z=(f16)v.z; o.w=(f16)v.w;
  reinterpret_cast<f16x4*>(d)[i] = o;
}

__global__ __launch_bounds__(256) void k_cvt(const float* __restrict__ s,
    f16* __restrict__ d, long n4){
  long i = (long)blockIdx.x*256 + threadIdx.x;
  if (i >= n4) return;
  float4 v = reinterpret_cast<const float4*>(s)[i];
  f16x4 o; o.x=(f16)v.x; o.y=(f16)v.y; o.z=(f16)v.z; o.w=(f16)v.w;
  reinterpret_cast<f16x4*>(d)[i] = o;
}

// conv weight transpose: cwT[l][m][d] = cw[l][d][KSZ-1-m]; grid.y: 0=up 1=dn
__global__ __launch_bounds__(256) void k_cvtconv2(const float* __restrict__ cwu,
    const float* __restrict__ cwd, float* __restrict__ cwTu, float* __restrict__ cwTd, int n){
  int i = blockIdx.x*256 + threadIdx.x;
  if (i >= n) return;
  const float* cw = blockIdx.y ? cwd : cwu;
  float* cwT      = blockIdx.y ? cwTd : cwTu;
  int d = i & (DIM-1); int m = (i >> 9) % KSZ; int l = i / (KSZ*DIM);
  cwT[i] = cw[((size_t)l*DIM + d)*KSZ + (KSZ-1-m)];
}

// ---------------- front-end ----------------
__global__ __launch_bounds__(64) void k_embnorm(const int* __restrict__ idx,
    const float* __restrict__ emb, const float* __restrict__ pos,
    const float* __restrict__ w, float* __restrict__ out){
  int row = blockIdx.x;                 // b*SEQ + t
  int t = row & (SEQ-1);
  int lane = threadIdx.x;
  long ebase = (long)idx[row]*DIM;
  long pbase = (long)t*DIM;
  float v[8]; float ss = 0.f;
  #pragma unroll
  for (int c=0;c<2;c++){
    int d = c*256 + lane*4;
    float4 e = *reinterpret_cast<const float4*>(emb + ebase + d);
    float4 p = *reinterpret_cast<const float4*>(pos + pbase + d);
    float x0 = e.x+p.x, x1 = e.y+p.y, x2 = e.z+p.z, x3 = e.w+p.w;
    v[c*4+0]=x0; v[c*4+1]=x1; v[c*4+2]=x2; v[c*4+3]=x3;
    ss += x0*x0 + x1*x1 + x2*x2 + x3*x3;
  }
  ss = wred(ss);
  float rs = rsqrtf(ss*(1.f/DIM) + 1e-6f);
  long ob = (long)row*DIM;
  #pragma unroll
  for (int c=0;c<2;c++){
    int d = c*256 + lane*4;
    float4 wv = *reinterpret_cast<const float4*>(w + d);
    float4 o;
    o.x = v[c*4+0]*rs*wv.x; o.y = v[c*4+1]*rs*wv.y;
    o.z = v[c*4+2]*rs*wv.z; o.w = v[c*4+3]*rs*wv.w;
    *reinterpret_cast<float4*>(out + ob + d) = o;
  }
}

__global__ void k_mem(const float* __restrict__ p, const float* __restrict__ gw,
                      const float* __restrict__ gb, float* __restrict__ mem){
  int i = blockIdx.x*blockDim.x + threadIdx.x;
  if (i >= BATCH*DIM) return;
  int b = i >> 9, d = i & (DIM-1);
  float acc = gb[d];
  const float* wr = gw + (long)d*DIM;
  const float* pr = p + b*DIM;
  for (int k=0;k<DIM;k+=4){
    float4 wv = *reinterpret_cast<const float4*>(wr+k);
    float4 pv = *reinterpret_cast<const float4*>(pr+k);
    acc += wv.x*pv.x + wv.y*pv.y + wv.z*pv.z + wv.w*pv.w;
  }
  mem[i] = sigm(acc);
}

__global__ void k_shift(const float* __restrict__ xn, const float* __restrict__ mem,
    const float* __restrict__ ts, float* __restrict__ out){
  int i = blockIdx.x*256 + threadIdx.x;   // over NTOK*DIM
  int d = i & (DIM-1); int row = i >> 9; int t = row & (SEQ-1); int b = row >> 10;
  float cur = xn[i];
  float v;
  if (t == 0) v = cur;
  else { float f = ts[d]; v = f*xn[i-DIM] + (1.f-f)*cur; }
  out[i] = v + mem[b*DIM + d];
}

// ---------------- norms / pid (f32 in, f16 out) ----------------
__global__ __launch_bounds__(64) void k_rms(const float* __restrict__ x,
    const float* __restrict__ w, f16* __restrict__ oh){
  int row = blockIdx.x; int lane = threadIdx.x;
  const float* xr = x + (long)row*DIM;
  float v[8]; float ss = 0.f;
  #pragma unroll
  for (int c=0;c<2;c++){
    int d = c*256 + lane*4;
    float4 f = *reinterpret_cast<const float4*>(xr + d);
    v[c*4+0]=f.x; v[c*4+1]=f.y; v[c*4+2]=f.z; v[c*4+3]=f.w;
    ss += f.x*f.x + f.y*f.y + f.z*f.z + f.w*f.w;
  }
  ss = wred(ss);
  float rs = rsqrtf(ss*(1.f/DIM) + 1e-6f);
  long ob = (long)row*DIM;
  #pragma unroll
  for (int c=0;c<2;c++){
    int d = c*256 + lane*4;
    float4 wv = *reinterpret_cast<const float4*>(w + d);
    f16x4 o;
    o.x = (f16)(v[c*4+0]*rs*wv.x); o.y = (f16)(v[c*4+1]*rs*wv.y);
    o.z = (f16)(v[c*4+2]*rs*wv.z); o.w = (f16)(v[c*4+3]*rs*wv.w);
    *reinterpret_cast<f16x4*>(oh + ob + d) = o;
  }
}

// cur_in = rmsnorm(silu(kp*C + ki*(I/i)), gn);  h1 = f16(rmsnorm(cur_in, nw))
__global__ __launch_bounds__(64) void k_pid(const float* __restrict__ C,
    const float* __restrict__ I, float inv_i,
    const float* __restrict__ kp, const float* __restrict__ ki,
    const float* __restrict__ gn, const float* __restrict__ nw,
    float* __restrict__ xin, f16* __restrict__ oh){
  int row = blockIdx.x; int lane = threadIdx.x;
  long base = (long)row*DIM;
  float u[8]; float ss = 0.f;
  #pragma unroll
  for (int c=0;c<2;c++){
    int d = c*256 + lane*4;
    float4 cv = *reinterpret_cast<const float4*>(C + base + d);
    float4 iv = *reinterpret_cast<const float4*>(I + base + d);
    float4 kpv = *reinterpret_cast<const float4*>(kp + d);
    float4 kiv = *reinterpret_cast<const float4*>(ki + d);
    float p0 = kpv.x*cv.x + kiv.x*(iv.x*inv_i);
    float p1 = kpv.y*cv.y + kiv.y*(iv.y*inv_i);
    float p2 = kpv.z*cv.z + kiv.z*(iv.z*inv_i);
    float p3 = kpv.w*cv.w + kiv.w*(iv.w*inv_i);
    float s0 = p0*sigm(p0), s1 = p1*sigm(p1), s2 = p2*sigm(p2), s3 = p3*sigm(p3);
    u[c*4+0]=s0; u[c*4+1]=s1; u[c*4+2]=s2; u[c*4+3]=s3;
    ss += s0*s0 + s1*s1 + s2*s2 + s3*s3;
  }
  ss = wred(ss);
  float rs1 = rsqrtf(ss*(1.f/DIM) + 1e-6f);
  float x2[8]; float ss2 = 0.f;
  #pragma unroll
  for (int c=0;c<2;c++){
    int d = c*256 + lane*4;
    float4 gv = *reinterpret_cast<const float4*>(gn + d);
    float y0 = u[c*4+0]*rs1*gv.x, y1 = u[c*4+1]*rs1*gv.y;
    float y2 = u[c*4+2]*rs1*gv.z, y3 = u[c*4+3]*rs1*gv.w;
    x2[c*4+0]=y0; x2[c*4+1]=y1; x2[c*4+2]=y2; x2[c*4+3]=y3;
    ss2 += y0*y0 + y1*y1 + y2*y2 + y3*y3;
    float4 o; o.x=y0; o.y=y1; o.z=y2; o.w=y3;
    *reinterpret_cast<float4*>(xin + base + d) = o;
  }
  ss2 = wred(ss2);
  float rs2 = rsqrtf(ss2*(1.f/DIM) + 1e-6f);
  #pragma unroll
  for (int c=0;c<2;c++){
    int d = c*256 + lane*4;
    float4 nv = *reinterpret_cast<const float4*>(nw + d);
    f16x4 o;
    o.x = (f16)(x2[c*4+0]*rs2*nv.x); o.y = (f16)(x2[c*4+1]*rs2*nv.y);
    o.z = (f16)(x2[c*4+2]*rs2*nv.z); o.w = (f16)(x2[c*4+3]*rs2*nv.w);
    *reinterpret_cast<f16x4*>(oh + base + d) = o;
  }
}

// ---------------- depthwise causal conv + silu, 8-wide vectorized ----------------
__global__ __launch_bounds__(256) void k_conv(const f16* __restrict__ h1,
    const float* __restrict__ cwT, const float* __restrict__ cb,
    f16* __restrict__ hc, int dil){
  int i = blockIdx.x*256 + threadIdx.x;   // over NTOK*DIM/8
  int d8 = (i & 63) << 3; int row = i >> 6; int t = row & (SEQ-1);
  float acc[8];
  {
    float4 b0 = *reinterpret_cast<const float4*>(&cb[d8]);
    float4 b1 = *reinterpret_cast<const float4*>(&cb[d8+4]);
    acc[0]=b0.x; acc[1]=b0.y; acc[2]=b0.z; acc[3]=b0.w;
    acc[4]=b1.x; acc[5]=b1.y; acc[6]=b1.z; acc[7]=b1.w;
  }
  #pragma unroll
  for (int m=0;m<KSZ;m++){
    if (t - m*dil >= 0){
      f16x8 h = *reinterpret_cast<const f16x8*>(&h1[(size_t)(row - m*dil)*DIM + d8]);
      float4 w0 = *reinterpret_cast<const float4*>(&cwT[m*DIM + d8]);
      float4 w1 = *reinterpret_cast<const float4*>(&cwT[m*DIM + d8 + 4]);
      acc[0]+=w0.x*(float)h[0]; acc[1]+=w0.y*(float)h[1];
      acc[2]+=w0.z*(float)h[2]; acc[3]+=w0.w*(float)h[3];
      acc[4]+=w1.x*(float)h[4]; acc[5]+=w1.y*(float)h[5];
      acc[6]+=w1.z*(float)h[6]; acc[7]+=w1.w*(float)h[7];
    }
  }
  f16x8 o;
  #pragma unroll
  for (int j=0;j<8;j++){ o[j] = (f16)(acc[j]*sigm(acc[j])); }
  *reinterpret_cast<f16x8*>(&hc[(size_t)row*DIM + d8]) = o;
}

// ---------------- unified tiled MFMA GEMM (champion: 2-phase gld16, full-drain) ----------------
// C[M,N] = A[M,K] . B[N,K]^T, f16 operands, f32 accumulate. BN=64, 4 waves split M.
// EPI 0: dual (B0=W1,B1=W3): OH = f16(silu(c0)*c1), ld HIDN
// EPI 1: w2: val = c0 + XIN; OF = val; I = (init? XIN : I) + val (ld DIM)
// EPI 2: logits: OF = c0 (ld VOCAB); 1-D grid, XCD-striped (mstripe = bid&15)
template<int BM,int KD,int EPI>
__global__ __launch_bounds__(256) void k_mm(
    const f16* __restrict__ A, const f16* __restrict__ B0, const f16* __restrict__ B1,
    const float* __restrict__ XIN, float* __restrict__ OF, float* __restrict__ I,
    f16* __restrict__ OH, int init){
  constexpr int WM = BM/4, MF = WM/16, NF = 4;
  constexpr int NMAT = (EPI==0) ? 2 : 1;
  constexpr int ATILE = BM*64;          // f16 elems per buffer
  constexpr int BTILE = NMAT*64*64;
  constexpr int STRIDE = ATILE + BTILE;
  constexpr int AI = (BM/4)/8;          // gload instrs per wave for A (8 rows each)
  constexpr int NT = KD/64;
  __shared__ f16 smem[2*STRIDE];
  int tid = threadIdx.x;
  int lane = tid & 63, wid = tid >> 6;
  int m0, n0;
  if constexpr (EPI==2){ int bid = blockIdx.x; m0 = (bid&15)*BM; n0 = (bid>>4)*64; }
  else { m0 = blockIdx.x*BM; n0 = blockIdx.y*64; }

  int lrow = lane >> 3, slot = lane & 7;   // staging decomposition

  // linear LDS dest + inverse-swizzled global source (rule #21):
  // LDS row r slot s holds global chunk s^(r&7); ds_read uses slot c^(r&7).
  auto stage = [&](int buf, int k0){
    f16* sA = smem + buf*STRIDE;
    f16* sB = sA + ATILE;
    #pragma unroll
    for (int j=0;j<AI;j++){
      int rowb = wid*(BM/4) + j*8;
      int row = rowb + lrow;
      gld16(A + (size_t)(m0+row)*KD + k0 + ((slot^(row&7))*8), sA + rowb*64);
    }
    #pragma unroll
    for (int j=0;j<2;j++){
      int rowb = wid*16 + j*8;
      int row = rowb + lrow;
      gld16(B0 + (size_t)(n0+row)*KD + k0 + ((slot^(row&7))*8), sB + rowb*64);
      if constexpr (EPI==0)
        gld16(B1 + (size_t)(n0+row)*KD + k0 + ((slot^(row&7))*8), sB + 4096 + rowb*64);
    }
  };

  f32x4 acc0[MF][NF] = {};
  f32x4 acc1[(EPI==0)?MF:1][(EPI==0)?NF:1] = {};

  stage(0, 0);
  __syncthreads();                       // drain prologue loads
  for (int t=0;t<NT;t++){
    int cur = t & 1;
    if (t+1 < NT) stage(cur^1, (t+1)*64);   // issue next tile BEFORE compute
    const f16* sA = smem + cur*STRIDE;
    const f16* sB = sA + ATILE;
    #pragma unroll
    for (int kk=0;kk<2;kk++){
      int kp0 = kk*4 + (lane>>4);        // 16B chunk index 0..7
      f16x8 af[MF], bf[NF], bg[(EPI==0)?NF:1];
      #pragma unroll
      for (int mf=0;mf<MF;mf++){
        int row = wid*WM + mf*16 + (lane&15);
        af[mf] = *reinterpret_cast<const f16x8*>(&sA[row*64 + (kp0^(row&7))*8]);
      }
      #pragma unroll
      for (int nf=0;nf<NF;nf++){
        int row = nf*16 + (lane&15);
        bf[nf] = *reinterpret_cast<const f16x8*>(&sB[row*64 + (kp0^(row&7))*8]);
        if constexpr (EPI==0)
          bg[nf] = *reinterpret_cast<const f16x8*>(&sB[4096 + row*64 + (kp0^(row&7))*8]);
      }
      #pragma unroll
      for (int mf=0;mf<MF;mf++){
        #pragma unroll
        for (int nf=0;nf<NF;nf++){
          acc0[mf][nf] = MFMA16(af[mf], bf[nf], acc0[mf][nf]);
          if constexpr (EPI==0)
            acc1[mf][nf] = MFMA16(af[mf], bg[nf], acc1[mf][nf]);
        }
      }
    }
    __syncthreads();    // drains stage(t+1) vmcnt + protects buffer reuse
  }

  // ---- LDS-staged coalesced epilogue (wave-private staging, stride 68) ----
  float* stg = (float*)smem + wid*(16*68);
  int dr = (lane>>4)*4, dc = lane&15;
  #pragma unroll
  for (int mf=0;mf<MF;mf++){
    #pragma unroll
    for (int nf=0;nf<NF;nf++){
      #pragma unroll
      for (int q=0;q<4;q++){
        float v;
        if constexpr (EPI==0){
          float x1 = acc0[mf][nf][q];
          v = x1*sigm(x1)*acc1[mf][nf][q];
        } else v = acc0[mf][nf][q];
        stg[(dr+q)*68 + nf*16 + dc] = v;
      }
    }
    int gmb = m0 + wid*WM + mf*16;
    if constexpr (EPI==0){
      #pragma unroll
      for (int pass=0;pass<2;pass++){
        int r = pass*8 + (lane>>3);
        int c = 8*(lane&7);
        float4 lo = *reinterpret_cast<float4*>(&stg[r*68 + c]);
        float4 hi = *reinterpret_cast<float4*>(&stg[r*68 + c + 4]);
        f16x8 o;
        o[0]=(f16)lo.x; o[1]=(f16)lo.y; o[2]=(f16)lo.z; o[3]=(f16)lo.w;
        o[4]=(f16)hi.x; o[5]=(f16)hi.y; o[6]=(f16)hi.z; o[7]=(f16)hi.w;
        *reinterpret_cast<f16x8*>(&OH[(size_t)(gmb+r)*HIDN + n0 + c]) = o;
      }
    } else if constexpr (EPI==1){
      #pragma unroll
      for (int pass=0;pass<4;pass++){
        int r = pass*4 + (lane>>4);
        int c = 4*(lane&15);
        float4 v = *reinterpret_cast<float4*>(&stg[r*68 + c]);
        size_t o = (size_t)(gmb+r)*DIM + n0 + c;
        float4 x = *reinterpret_cast<const float4*>(&XIN[o]);
        v.x += x.x; v.y += x.y; v.z += x.z; v.w += x.w;
        *reinterpret_cast<float4*>(&OF[o]) = v;
        float4 iv;
        if (init) iv = x;
        else      iv = *reinterpret_cast<const float4*>(&I[o]);
        iv.x += v.x; iv.y += v.y; iv.z += v.z; iv.w += v.w;
        *reinterpret_cast<float4*>(&I[o]) = iv;
      }
    } else {
      #pragma unroll
      for (int pass=0;pass<4;pass++){
        int r = pass*4 + (lane>>4);
        int c = 4*(lane&15);
        float4 v = *reinterpret_cast<float4*>(&stg[r*68 + c]);
        *reinterpret_cast<float4*>(&OF[(size_t)(gmb+r)*VOCAB + n0 + c]) = v;
      }
    }
  }
}

// ---------------- mix: parallel scan, one wave per (b,d) column ----------------
__global__ __launch_bounds__(64) void k_mix(float* __restrict__ x){
  int col = blockIdx.x;                 // 0..BATCH*DIM-1
  int b = col >> 9, d = col & (DIM-1);
  int lane = threadIdx.x;
  long o = (long)b*SEQ*DIM + d + (long)lane*16*DIM;
  float v[16]; float s = 0.f;
  #pragma unroll
  for (int j=0;j<16;j++){ v[j] = x[o + (long)j*DIM]; s += v[j]; }
  float t = s;
  #pragma unroll
  for (int off=1; off<64; off<<=1){
    float u = __shfl_up(t, off, 64);
    if (lane >= off) t += u;
  }
  float run = t - s;   // exclusive prefix
  #pragma unroll
  for (int j=0;j<16;j++){
    run += v[j];
    int tt = lane*16 + j;
    x[o + (long)j*DIM] = v[j] + MIXW*run/(float)(tt+1);
  }
}

// ---------------- sgate (low-rank gate) ----------------
__global__ __launch_bounds__(256) void k_sgate(const float* __restrict__ xnew,
    const float* __restrict__ xold, const float* __restrict__ nw,
    const float* __restrict__ dw, const float* __restrict__ db,
    const float* __restrict__ uw, const float* __restrict__ ub,
    float* __restrict__ out){
  __shared__ float raw[DIM];
  __shared__ float xn[DIM];
  __shared__ float part[256];
  __shared__ float hb[RANK];
  int row = blockIdx.x, tid = threadIdx.x;
  long base = (long)row*DIM;
  float ss = 0.f;
  for (int d=tid; d<DIM; d+=256){ float v = xnew[base+d]; raw[d]=v; ss += v*v; }
  ss = wred(ss);
  if ((tid&63)==0) part[tid>>6] = ss;
  __syncthreads();
  float tot = part[0]+part[1]+part[2]+part[3];
  float rs = rsqrtf(tot*(1.f/DIM)+1e-6f);
  for (int d=tid; d<DIM; d+=256) xn[d] = raw[d]*rs*nw[d];
  __syncthreads();
  int rr = tid & 63, q = tid >> 6;
  float p = 0.f;
  const float* dwr = dw + (long)rr*DIM + q*128;
  const float* xq = xn + q*128;
  #pragma unroll 8
  for (int d=0; d<128; d+=4){
    float4 wv = *reinterpret_cast<const float4*>(dwr+d);
    p += xq[d]*wv.x + xq[d+1]*wv.y + xq[d+2]*wv.z + xq[d+3]*wv.w;
  }
  part[tid] = p;
  __syncthreads();
  if (tid < RANK){
    float h = part[tid] + part[64+tid] + part[128+tid] + part[192+tid] + db[tid];
    hb[tid] = h * sigm(h);
  }
  __syncthreads();
  for (int d=tid; d<DIM; d+=256){
    float a = ub[d];
    const float* ur = uw + (long)d*RANK;
    #pragma unroll
    for (int rj=0;rj<RANK;rj+=4){
      float4 uv = *reinterpret_cast<const float4*>(ur+rj);
      a += hb[rj]*uv.x + hb[rj+1]*uv.y + hb[rj+2]*uv.z + hb[rj+3]*uv.w;
    }
    float g = sigm(a);
    out[base+d] = g*raw[d] + (1.f-g)*xold[base+d];
  }
}

// ---------------- host orchestration ----------------
extern "C" void kernel_launch(void* const* d_in, const int* in_sizes, int n_in,
                              void* d_out, int out_size, void* d_ws, size_t ws_size,
                              hipStream_t stream){
  const int*   idx           = (const int*)d_in[0];
  const float* emb           = (const float*)d_in[1];
  const float* pos           = (const float*)d_in[2];
  const float* emb_norm_w    = (const float*)d_in[3];
  const float* token_shift   = (const float*)d_in[4];
  const float* mem_gate_w    = (const float*)d_in[5];
  const float* mem_gate_b    = (const float*)d_in[6];
  const float* memory_p      = (const float*)d_in[7];
  const float* sg_norm       = (const float*)d_in[8];
  const float* sg_down_w     = (const float*)d_in[9];
  const float* sg_down_b     = (const float*)d_in[10];
  const float* sg_up_w       = (const float*)d_in[11];
  const float* sg_up_b       = (const float*)d_in[12];
  const float* final_norm_w  = (const float*)d_in[13];
  struct StackP { const float *nw, *cw, *cb, *w1, *w2, *w3, *kp, *ki, *gn; };
  StackP up { (const float*)d_in[14], (const float*)d_in[15], (const float*)d_in[16],
              (const float*)d_in[17], (const float*)d_in[18], (const float*)d_in[19],
              (const float*)d_in[20], (const float*)d_in[21], (const float*)d_in[23] };
  StackP dn { (const float*)d_in[24], (const float*)d_in[25], (const float*)d_in[26],
              (const float*)d_in[27], (const float*)d_in[28], (const float*)d_in[29],
              (const float*)d_in[30], (const float*)d_in[31], (const float*)d_in[33] };

  char* wp = (char*)d_ws;
  auto alloc = [&](size_t bytes)->void*{
    void* p = (void*)wp; wp += (bytes + 255) & ~(size_t)255; return p;
  };
  float* A0  = (float*)alloc((size_t)NTOK*DIM*4);
  float* A1  = (float*)alloc((size_t)NTOK*DIM*4);
  float* Cb  = (float*)alloc((size_t)NTOK*DIM*4);
  float* Ib  = (float*)alloc((size_t)NTOK*DIM*4);
  float* XIN = (float*)alloc((size_t)NTOK*DIM*4);
  f16*   H1  = (f16*)alloc((size_t)NTOK*DIM*2);
  f16*   HC  = (f16*)alloc((size_t)NTOK*DIM*2);
  f16*   G   = (f16*)alloc((size_t)NTOK*HIDN*2);
  const size_t WSZ = (size_t)NLAYERS*HIDN*DIM;   // per weight family per stack
  f16*   UpW1 = (f16*)alloc(WSZ*2);
  f16*   UpW2 = (f16*)alloc(WSZ*2);
  f16*   UpW3 = (f16*)alloc(WSZ*2);
  f16*   DnW1 = (f16*)alloc(WSZ*2);
  f16*   DnW2 = (f16*)alloc(WSZ*2);
  f16*   DnW3 = (f16*)alloc(WSZ*2);
  f16*   Ef   = (f16*)alloc((size_t)VOCAB*DIM*2);
  float* UpCT = (float*)alloc((size_t)NLAYERS*KSZ*DIM*4);
  float* DnCT = (float*)alloc((size_t)NLAYERS*KSZ*DIM*4);
  float* MEM  = (float*)alloc((size_t)BATCH*DIM*4);

  static const int updil[NLAYERS] = {1,2,4,8,16,32};
  static const int dndil[NLAYERS] = {32,16,8,4,2,1};

  // one-time weight conversions (fused: 3 launches total)
  {
    long n4 = WSZ/4;
    int g = (int)((n4 + 255)/256);
    k_cvt6<<<dim3(g,6),256,0,stream>>>(up.w1, up.w2, up.w3, dn.w1, dn.w2, dn.w3,
                                       UpW1, UpW2, UpW3, DnW1, DnW2, DnW3, n4);
    long e4 = (long)VOCAB*DIM/4;
    k_cvt<<<(int)((e4+255)/256),256,0,stream>>>(emb, Ef, e4);
    int nc = NLAYERS*KSZ*DIM;
    k_cvtconv2<<<dim3((nc+255)/256,2),256,0,stream>>>(up.cw, dn.cw, UpCT, DnCT, nc);
  }

  k_embnorm<<<NTOK,64,0,stream>>>(idx, emb, pos, emb_norm_w, Cb);
  k_mem<<<(BATCH*DIM+255)/256,256,0,stream>>>(memory_p, mem_gate_w, mem_gate_b, MEM);
  k_shift<<<NTOK*DIM/256,256,0,stream>>>(Cb, MEM, token_shift, A0);

  auto run_stack = [&](const float* xs, const StackP& S, const float* CT,
                       const f16* W1f, const f16* W2f, const f16* W3f, const int* dil){
    for (int l=0;l<NLAYERS;l++){
      const float* bin;
      if (l==0){
        bin = xs;
        k_rms<<<NTOK,64,0,stream>>>(xs, S.nw + l*DIM, H1);
      } else {
        k_pid<<<NTOK,64,0,stream>>>(Cb, Ib, 1.f/(float)l,
            S.kp+(l-1)*DIM, S.ki+(l-1)*DIM, S.gn+(l-1)*DIM, S.nw+l*DIM, XIN, H1);
        bin = XIN;
      }
      k_conv<<<NTOK*DIM/8/256,256,0,stream>>>(H1, CT + (size_t)l*KSZ*DIM, S.cb + l*DIM, HC, dil[l]);
      k_mm<128,512,0><<<dim3(NTOK/128, HIDN/64),256,0,stream>>>(
          HC, W1f + (size_t)l*HIDN*DIM, W3f + (size_t)l*HIDN*DIM,
          nullptr, nullptr, nullptr, G, 0);
      k_mm<64,1024,1><<<dim3(NTOK/64, DIM/64),256,0,stream>>>(
          G, W2f + (size_t)l*DIM*HIDN, nullptr,
          bin, Cb, Ib, nullptr, (l==0)?1:0);
    }
  };

  // stack 1 (up)
  run_stack(A0, up, UpCT, UpW1, UpW2, UpW3, updil);
  k_mix<<<BATCH*DIM,64,0,stream>>>(Cb);
  k_sgate<<<NTOK,256,0,stream>>>(Cb, A0, sg_norm, sg_down_w, sg_down_b, sg_up_w, sg_up_b, A1);
  // stack 2 (down)
  run_stack(A1, dn, DnCT, DnW1, DnW2, DnW3, dndil);
  k_mix<<<BATCH*DIM,64,0,stream>>>(Cb);
  k_sgate<<<NTOK,256,0,stream>>>(Cb, A0, sg_norm+DIM, sg_down_w+RANK*DIM, sg_down_b+RANK,
                                 sg_up_w+DIM*RANK, sg_up_b+DIM, A1);
  // stack 3 (up again)
  run_stack(A1, up, UpCT, UpW1, UpW2, UpW3, updil);
  k_mix<<<BATCH*DIM,64,0,stream>>>(Cb);
  k_sgate<<<NTOK,256,0,stream>>>(Cb, A1, sg_norm+2*DIM, sg_down_w+2*RANK*DIM, sg_down_b+2*RANK,
                                 sg_up_w+2*DIM*RANK, sg_up_b+2*DIM, Cb);
  // final norm + logits (XCD-striped 1-D grid: bid&15 = m-stripe)
  k_rms<<<NTOK,64,0,stream>>>(Cb, final_norm_w, H1);
  k_mm<128,512,2><<<16*(VOCAB/64),256,0,stream>>>(
      H1, Ef, nullptr, nullptr, (float*)d_out, nullptr, nullptr, 0);
}